// Round 16
// baseline (283.944 us; speedup 1.0000x reference)
//
#include <hip/hip_runtime.h>
#include <math.h>

#define T_LEN 256
#define B_SZ  32
#define ZD    64
#define HD    256
#define NSAMP (B_SZ*(T_LEN-1))   // 8160
#define MBLK  32                 // samples per ODE block -> 255 blocks

typedef unsigned short u16;
typedef __attribute__((ext_vector_type(8))) _Float16 h8v;
typedef __attribute__((ext_vector_type(2))) _Float16 h2v;
typedef __attribute__((ext_vector_type(8))) unsigned short us8v;
typedef __attribute__((ext_vector_type(4))) float  f4v;

// ws layout (float offsets). Packs overlay P0 (prep runs AFTER rnn consumed P0).
#define SZ_ZB   (B_SZ*(T_LEN-1)*ZD)     // 522240
#define SZ_P0   ((T_LEN-1)*B_SZ*ZD)     // 522240 (plain [s][b][j] layout)
#define OFF_ZB  0
#define OFF_P0  (OFF_ZB + SZ_ZB)
// fp16 pack offsets in u16 units, based at (u16*)(ws + OFF_P0); 163840 u16 = 320KB <= P0 region
#define PK_WB  0         // Wh1^T fragments (phase B), 65536
#define PK_WC  65536     // Wh1 fragments (phase C), 65536
#define PK_WA  131072    // Wh0^T fragments (phase A), 16384
#define PK_WD  147456    // Wh0 fragments (phase D), 16384

__device__ __forceinline__ u16 f2h(float x) {
    _Float16 h = (_Float16)x;
    return __builtin_bit_cast(u16, h);
}
__device__ __forceinline__ float fast_tanh(float x) {
    float xc = fminf(fmaxf(x, -18.f), 18.f);
    float e2 = __builtin_amdgcn_exp2f(xc * 2.8853900817779268f);  // e^(2x)
    return (e2 - 1.f) * __builtin_amdgcn_rcpf(e2 + 1.f);
}
__device__ __forceinline__ f4v mfma16h(h8v a, h8v b, f4v c) {
    return __builtin_amdgcn_mfma_f32_16x16x32_f16(a, b, c, 0, 0, 0);
}
__device__ __forceinline__ h8v lds_frag(const u16* buf, int byt) {
    return *(const h8v*)((const char*)buf + byt);
}
__device__ __forceinline__ void store_h(u16* buf, int byt, float v) {
    *(u16*)((char*)buf + byt) = f2h(v);
}
// LDS-only barrier: does NOT drain vmcnt (global loads/stores stay in flight).
__device__ __forceinline__ void barrier_lds() {
    asm volatile("s_waitcnt lgkmcnt(0)\n\ts_barrier" ::: "memory");
}

__device__ __forceinline__ h2v bch2(unsigned u) { return __builtin_bit_cast(h2v, u); }
__device__ __forceinline__ unsigned packh2(float a, float b) {
    h2v v; v[0] = (_Float16)a; v[1] = (_Float16)b;
    return __builtin_bit_cast(unsigned, v);
}
#if __has_builtin(__builtin_amdgcn_fdot2)
__device__ __forceinline__ float fdot2f(unsigned a, unsigned b, float c) {
    return __builtin_amdgcn_fdot2(bch2(a), bch2(b), c, false);
}
#else
__device__ __forceinline__ float fdot2f(unsigned a, unsigned b, float c) {
    h2v x = bch2(a), y = bch2(b);
    return c + (float)x[0] * (float)y[0] + (float)x[1] * (float)y[1];
}
#endif

// Yoshida coefficients * h_step (h=0.02). e%7: even=drift(+cs*h on q from dHp), odd=kick(-ds*h on p from dHq)
__device__ __constant__ float c_coef[7] = {
     0.013512071919596578f,
    -0.027024143839193156f,
    -0.003512071919596575f,
     0.034048287678386313f,
    -0.003512071919596575f,
    -0.027024143839193156f,
     0.013512071919596578f
};

// ---------------- prep: pack fp16 weights into MFMA B-fragment order ----------
// frag (nt,ks): lane = lg*16+col16 holds B[ks*32+lg*8+i][nt*16+col16], i=0..7
// idx = ((nt*KS + ks)*64 + lane)*8 + i
__global__ __launch_bounds__(256) void prep_pack(
    const float* __restrict__ Wh1, const float* __restrict__ Wh0, u16* __restrict__ pk)
{
    int i = blockIdx.x * 256 + threadIdx.x;      // 0..65535
    u16 h = f2h(Wh1[i]);
    {   // WB: B[k][n] = Wh1[n][k]; n=i>>8, k=i&255 (KS=8)
        int n = i >> 8, k = i & 255;
        int idx = ((((n >> 4) * 8 + (k >> 5)) * 64) + ((k >> 3) & 3) * 16 + (n & 15)) * 8 + (k & 7);
        pk[PK_WB + idx] = h;
    }
    {   // WC: B[k][n] = Wh1[k][n]; k=i>>8, n=i&255 (KS=8)
        int k = i >> 8, n = i & 255;
        int idx = ((((n >> 4) * 8 + (k >> 5)) * 64) + ((k >> 3) & 3) * 16 + (n & 15)) * 8 + (k & 7);
        pk[PK_WC + idx] = h;
    }
    if (i < HD * ZD) {
        u16 h0 = f2h(Wh0[i]);                    // Wh0[256][64]
        {   // WA: B[k][n] = Wh0[n][k]; n=i>>6 (0..255), k=i&63 (KS=2)
            int n = i >> 6, k = i & 63;
            int idx = ((((n >> 4) * 2 + (k >> 5)) * 64) + ((k >> 3) & 3) * 16 + (n & 15)) * 8 + (k & 7);
            pk[PK_WA + idx] = h0;
        }
        {   // WD: B[k][n] = Wh0[k][n]; k=i>>6, n=i&63 (KS=8, NT=4)
            int k = i >> 6, n = i & 63;
            int idx = ((((n >> 4) * 8 + (k >> 5)) * 64) + ((k >> 3) & 3) * 16 + (n & 15)) * 8 + (k & 7);
            pk[PK_WD + idx] = h0;
        }
    }
}

// ---------------- P0 = x[:,255-s,:] @ Wih0^T + bih0 + bhh0,  P0[s][b][j] -------
__global__ __launch_bounds__(256) void p0_kernel(
    const float* __restrict__ x, const float* __restrict__ Wih0,
    const float* __restrict__ bih0, const float* __restrict__ bhh0,
    float* __restrict__ P0)
{
    __shared__ float xs[B_SZ * 128];
    int s = blockIdx.x;
    int t = (T_LEN - 1) - s;
    int tid = threadIdx.x;
#pragma unroll
    for (int p = 0; p < 4; ++p) {
        int idx4 = tid + p * 256;
        int b = idx4 >> 5;
        int k = (idx4 & 31) * 4;
        *(float4*)&xs[b * 128 + k] = *(const float4*)&x[b * (T_LEN * 128) + t * 128 + k];
    }
    int j = tid & 63, bq = tid >> 6;
    float wr[128];
#pragma unroll
    for (int k4 = 0; k4 < 32; ++k4) {
        float4 v = *(const float4*)&Wih0[j * 128 + k4 * 4];
        wr[k4*4+0]=v.x; wr[k4*4+1]=v.y; wr[k4*4+2]=v.z; wr[k4*4+3]=v.w;
    }
    float bias = bih0[j] + bhh0[j];
    __syncthreads();
    for (int p = 0; p < 8; ++p) {
        int b = bq * 8 + p;
        float a0 = bias, a1 = 0.f;
#pragma unroll
        for (int k4 = 0; k4 < 32; ++k4) {
            float4 v = *(const float4*)&xs[b * 128 + k4 * 4];
            a0 += v.x * wr[k4*4+0] + v.y * wr[k4*4+1];
            a1 += v.z * wr[k4*4+2] + v.w * wr[k4*4+3];
        }
        P0[(s * B_SZ + b) * ZD + j] = a0 + a1;
    }
}

// ---------------- RNN scan: 32 blocks (1/batch), 2 waves, fdot2 + fp16 state --
__global__ __launch_bounds__(128, 1) void rnn_kernel(
    const float* __restrict__ P0, const float* __restrict__ h0in,
    const float* __restrict__ Whh0, const float* __restrict__ Wih1,
    const float* __restrict__ Whh1, const float* __restrict__ bih1,
    const float* __restrict__ bhh1,
    float* __restrict__ zbuf, float* __restrict__ out)
{
    __shared__ __align__(16) u16 h0buf[2][ZD];
    __shared__ __align__(16) u16 h1buf[2][ZD];
    const int b = blockIdx.x;
    const int tid = threadIdx.x;
    const int w = tid >> 6, j = tid & 63;

    unsigned wa[32], wb[32];
    float bias1 = 0.f;
    if (w == 0) {
#pragma unroll
        for (int q = 0; q < 16; ++q) {
            float4 v = *(const float4*)&Whh0[j * 64 + q * 4];
            wa[q*2+0] = packh2(v.x, v.y);
            wa[q*2+1] = packh2(v.z, v.w);
        }
        h0buf[0][j] = f2h(h0in[j]);
    } else {
#pragma unroll
        for (int q = 0; q < 16; ++q) {
            float4 v = *(const float4*)&Wih1[j * 64 + q * 4];
            wa[q*2+0] = packh2(v.x, v.y);
            wa[q*2+1] = packh2(v.z, v.w);
            float4 u = *(const float4*)&Whh1[j * 64 + q * 4];
            wb[q*2+0] = packh2(u.x, u.y);
            wb[q*2+1] = packh2(u.z, u.w);
        }
        bias1 = bih1[j] + bhh1[j];
        h1buf[0][j] = f2h(h0in[ZD + j]);
    }
    float a_cur = 0.f, a_nxt = 0.f;
    if (w == 0) {
        a_cur = P0[(0 * B_SZ + b) * ZD + j];
        a_nxt = P0[(1 * B_SZ + b) * ZD + j];
    }
    __syncthreads();

    for (int t = 0; t < T_LEN; ++t) {
        if (w == 0) {
            if (t < T_LEN - 1) {
                float a_new = (t + 2 < T_LEN - 1) ? P0[((t + 2) * B_SZ + b) * ZD + j] : 0.f;
                const u16* hp = h0buf[t & 1];
                float c0 = a_cur, c1 = 0.f, c2 = 0.f, c3 = 0.f;
#pragma unroll
                for (int pp = 0; pp < 8; ++pp) {
                    uint4 ha = *(const uint4*)(hp + pp * 8);
                    c0 = fdot2f(wa[pp*4+0], ha.x, c0);
                    c1 = fdot2f(wa[pp*4+1], ha.y, c1);
                    c2 = fdot2f(wa[pp*4+2], ha.z, c2);
                    c3 = fdot2f(wa[pp*4+3], ha.w, c3);
                }
                float y = fast_tanh((c0 + c1) + (c2 + c3));
                h0buf[(t & 1) ^ 1][j] = f2h(y);
                a_cur = a_nxt; a_nxt = a_new;
            }
        } else {
            if (t >= 1) {
                const u16* hp = h0buf[t & 1];         // y0[t-1]
                const u16* gp = h1buf[(t + 1) & 1];   // y1[t-2]
                float c0 = bias1, c1 = 0.f, c2 = 0.f, c3 = 0.f;
                float d0 = 0.f, d1 = 0.f, d2 = 0.f, d3 = 0.f;
#pragma unroll
                for (int pp = 0; pp < 8; ++pp) {
                    uint4 ha = *(const uint4*)(hp + pp * 8);
                    uint4 ga = *(const uint4*)(gp + pp * 8);
                    c0 = fdot2f(wa[pp*4+0], ha.x, c0);
                    c1 = fdot2f(wa[pp*4+1], ha.y, c1);
                    c2 = fdot2f(wa[pp*4+2], ha.z, c2);
                    c3 = fdot2f(wa[pp*4+3], ha.w, c3);
                    d0 = fdot2f(wb[pp*4+0], ga.x, d0);
                    d1 = fdot2f(wb[pp*4+1], ga.y, d1);
                    d2 = fdot2f(wb[pp*4+2], ga.z, d2);
                    d3 = fdot2f(wb[pp*4+3], ga.w, d3);
                }
                float y = fast_tanh(((c0 + c1) + (c2 + c3)) + ((d0 + d1) + (d2 + d3)));
                h1buf[t & 1][j] = f2h(y);
                int s = t - 1;
                int tau = (T_LEN - 2) - s;
                zbuf[(b * (T_LEN - 1) + tau) * ZD + j] = y;
                if (s == 0)
                    out[(b * T_LEN + (T_LEN - 1)) * ZD + j] = y;
            }
        }
        barrier_lds();   // orders h0 handoff; global loads/stores stay in flight
    }
}

// ---------------- ODE: round-13 structure (empirical optimum) + zq row pad ----
// zq stride 68 floats removes the 4-way bank conflict on phase-D f32 updates;
// pad is compile-time address arithmetic, zero extra instructions in hot loops.
__global__ __launch_bounds__(512, 1) void ode_kernel(
    const float* __restrict__ zbuf,
    const float* __restrict__ bh0, const float* __restrict__ bh1,
    const float* __restrict__ Wout, const u16* __restrict__ pk,
    float* __restrict__ out)
{
    __shared__ __align__(16) u16 sWA[16384];   // 32KB, WA frags
    __shared__ __align__(16) u16 sWD[16384];   // 32KB, WD frags
    __shared__ __align__(16) u16 aA[32 * 256]; // 16KB, swizzled fp16 activations
    __shared__ __align__(16) u16 aB[32 * 256]; // 16KB
    __shared__ __align__(16) u16 zh[32 * 64];  // 4KB, swizzled fp16 z
    __shared__ __align__(16) float zq[32 * 68];// 8.5KB, fp32 z (padded rows)

    const int tid  = threadIdx.x;
    const int w    = tid >> 6, lane = tid & 63;
    const int l15  = lane & 15, lg = lane >> 4;
    const int base = blockIdx.x * MBLK;

    // ---- load Wh1 fragments into VGPRs (time-shared WB<->WC per round 11/13)
    h8v wgt[2][8];
    {
        const h8v* pWB = (const h8v*)(pk + PK_WB);
#pragma unroll
        for (int t = 0; t < 2; ++t)
#pragma unroll
            for (int ks = 0; ks < 8; ++ks)
                wgt[t][ks] = pWB[((w * 2 + t) * 8 + ks) * 64 + lane];
    }
    // ---- stage WA/WD into LDS (pack order)
    {
        const us8v* gA = (const us8v*)(pk + PK_WA);
        const us8v* gD = (const us8v*)(pk + PK_WD);
#pragma unroll
        for (int r = 0; r < 4; ++r) {
            int idx = tid + r * 512;             // 2048 vec8 per 32KB
            ((us8v*)sWA)[idx] = gA[idx];
            ((us8v*)sWD)[idx] = gD[idx];
        }
    }

    float bh0v[2], bh1v[2], wov[2];
#pragma unroll
    for (int t = 0; t < 2; ++t) {
        int col = (w * 2 + t) * 16 + l15;
        bh0v[t] = bh0[col]; bh1v[t] = bh1[col]; wov[t] = Wout[col];
    }

    // ---- stage z tile (32x64): zq f32 (padded) + zh swizzled fp16
    {
        int m = tid >> 4, c4 = tid & 15;
        float4 v = *(const float4*)&zbuf[(size_t)(base + m) * ZD + c4 * 4];
        *(float4*)&zq[m * 68 + c4 * 4] = v;
        ushort4 hh;
        hh.x = f2h(v.x); hh.y = f2h(v.y); hh.z = f2h(v.z); hh.w = f2h(v.w);
        int byt = (m * 128 + c4 * 8) ^ ((m & 7) << 4);
        *(ushort4*)((char*)zh + byt) = hh;
    }
    __syncthreads();

#pragma unroll 1
    for (int e = 0; e < 28; ++e) {
        int ei = e % 7;
        f4v acc[2][2];
#pragma unroll
        for (int mt = 0; mt < 2; ++mt)
#pragma unroll
            for (int t = 0; t < 2; ++t) acc[mt][t] = f4v{0.f, 0.f, 0.f, 0.f};

        // ---- Phase A: pre0 = z @ Wh0^T (K=64, N=256; wave w owns nt=2w,2w+1)
#pragma unroll
        for (int ks = 0; ks < 2; ++ks) {
            h8v az[2];
#pragma unroll
            for (int mt = 0; mt < 2; ++mt) {
                int byt = ((mt * 16 + l15) * 128 + ks * 64 + lg * 16) ^ ((l15 & 7) << 4);
                az[mt] = lds_frag(zh, byt);
            }
#pragma unroll
            for (int t = 0; t < 2; ++t) {
                h8v bw = lds_frag(sWA, (((w * 2 + t) * 2 + ks) * 64 + lane) * 16);
#pragma unroll
                for (int mt = 0; mt < 2; ++mt)
                    acc[mt][t] = mfma16h(az[mt], bw, acc[mt][t]);
            }
        }
        float h0reg[2][2][4];
#pragma unroll
        for (int mt = 0; mt < 2; ++mt)
#pragma unroll
            for (int t = 0; t < 2; ++t)
#pragma unroll
                for (int r = 0; r < 4; ++r) {
                    float tv = fast_tanh(acc[mt][t][r] + bh0v[t]);
                    h0reg[mt][t][r] = tv;
                    int row = mt * 16 + lg * 4 + r;
                    int col = (w * 2 + t) * 16 + l15;
                    store_h(aA, (row * 512 + col * 2) ^ ((row & 7) << 4), tv);
                }
        __syncthreads();

        // ---- Phase B: pre1 = h0 @ Wh1^T (wgt = WB); g -> aB
#pragma unroll
        for (int mt = 0; mt < 2; ++mt)
#pragma unroll
            for (int t = 0; t < 2; ++t) acc[mt][t] = f4v{0.f, 0.f, 0.f, 0.f};
#pragma unroll
        for (int ks = 0; ks < 8; ++ks) {
            h8v ah[2];
#pragma unroll
            for (int mt = 0; mt < 2; ++mt) {
                int byt = ((mt * 16 + l15) * 512 + ks * 64 + lg * 16) ^ ((l15 & 7) << 4);
                ah[mt] = lds_frag(aA, byt);
            }
#pragma unroll
            for (int t = 0; t < 2; ++t)
#pragma unroll
                for (int mt = 0; mt < 2; ++mt)
                    acc[mt][t] = mfma16h(ah[mt], wgt[t][ks], acc[mt][t]);
        }
#pragma unroll
        for (int mt = 0; mt < 2; ++mt)
#pragma unroll
            for (int t = 0; t < 2; ++t)
#pragma unroll
                for (int r = 0; r < 4; ++r) {
                    float tv = fast_tanh(acc[mt][t][r] + bh1v[t]);
                    float g = wov[t] * (1.f - tv * tv);
                    int row = mt * 16 + lg * 4 + r;
                    int col = (w * 2 + t) * 16 + l15;
                    store_h(aB, (row * 512 + col * 2) ^ ((row & 7) << 4), g);
                }
        // swap wgt to WC (WAR orders after last B-MFMA; hides under barrier + C)
        {
            const h8v* pWC = (const h8v*)(pk + PK_WC);
#pragma unroll
            for (int t = 0; t < 2; ++t)
#pragma unroll
                for (int ks = 0; ks < 8; ++ks)
                    wgt[t][ks] = pWC[((w * 2 + t) * 8 + ks) * 64 + lane];
        }
        __syncthreads();

        // ---- Phase C: u = (g @ Wh1) * (1 - h0^2)  (wgt = WC); u -> aA in place
#pragma unroll
        for (int mt = 0; mt < 2; ++mt)
#pragma unroll
            for (int t = 0; t < 2; ++t) acc[mt][t] = f4v{0.f, 0.f, 0.f, 0.f};
#pragma unroll
        for (int ks = 0; ks < 8; ++ks) {
            h8v ah[2];
#pragma unroll
            for (int mt = 0; mt < 2; ++mt) {
                int byt = ((mt * 16 + l15) * 512 + ks * 64 + lg * 16) ^ ((l15 & 7) << 4);
                ah[mt] = lds_frag(aB, byt);
            }
#pragma unroll
            for (int t = 0; t < 2; ++t)
#pragma unroll
                for (int mt = 0; mt < 2; ++mt)
                    acc[mt][t] = mfma16h(ah[mt], wgt[t][ks], acc[mt][t]);
        }
#pragma unroll
        for (int mt = 0; mt < 2; ++mt)
#pragma unroll
            for (int t = 0; t < 2; ++t)
#pragma unroll
                for (int r = 0; r < 4; ++r) {
                    float hv = h0reg[mt][t][r];
                    float u = acc[mt][t][r] * (1.f - hv * hv);
                    int row = mt * 16 + lg * 4 + r;
                    int col = (w * 2 + t) * 16 + l15;
                    store_h(aA, (row * 512 + col * 2) ^ ((row & 7) << 4), u);
                }
        // swap wgt back to WB for next eval (hides under phase D)
        {
            const h8v* pWB = (const h8v*)(pk + PK_WB);
#pragma unroll
            for (int t = 0; t < 2; ++t)
#pragma unroll
                for (int ks = 0; ks < 8; ++ks)
                    wgt[t][ks] = pWB[((w * 2 + t) * 8 + ks) * 64 + lane];
        }
        __syncthreads();

        // ---- Phase D (waves 4-7): dz = u @ Wh0 (N=64); update zq/zh
        if (w >= 4) {
            int nt = w - 4;
            f4v accd[2];
            accd[0] = f4v{0.f, 0.f, 0.f, 0.f};
            accd[1] = f4v{0.f, 0.f, 0.f, 0.f};
#pragma unroll
            for (int ks = 0; ks < 8; ++ks) {
                h8v ah[2];
#pragma unroll
                for (int mt = 0; mt < 2; ++mt) {
                    int byt = ((mt * 16 + l15) * 512 + ks * 64 + lg * 16) ^ ((l15 & 7) << 4);
                    ah[mt] = lds_frag(aA, byt);
                }
                h8v bw = lds_frag(sWD, ((nt * 8 + ks) * 64 + lane) * 16);
#pragma unroll
                for (int mt = 0; mt < 2; ++mt)
                    accd[mt] = mfma16h(ah[mt], bw, accd[mt]);
            }
            float cf = c_coef[ei];
            int col = nt * 16 + l15;
            bool drift = (ei & 1) == 0;
            bool active = drift ? (col >= 32) : (col < 32);
            int dcol = drift ? (col - 32) : (col + 32);
            if (active) {
#pragma unroll
                for (int mt = 0; mt < 2; ++mt)
#pragma unroll
                    for (int r = 0; r < 4; ++r) {
                        int row = mt * 16 + lg * 4 + r;
                        float nz = zq[row * 68 + dcol] + cf * accd[mt][r];
                        zq[row * 68 + dcol] = nz;
                        store_h(zh, (row * 128 + dcol * 2) ^ ((row & 7) << 4), nz);
                    }
            }
        }
        __syncthreads();
    }

    // ---- write out[b][tau][:] = z
    {
        int m = tid >> 4, c4 = tid & 15;
        int sidx = base + m;
        int b = sidx / 255;
        int tau = sidx - b * 255;
        float4 v = *(const float4*)&zq[m * 68 + c4 * 4];
        *(float4*)&out[((size_t)(b * T_LEN + tau)) * ZD + c4 * 4] = v;
    }
}

extern "C" void kernel_launch(void* const* d_in, const int* in_sizes, int n_in,
                              void* d_out, int out_size, void* d_ws, size_t ws_size,
                              hipStream_t stream)
{
    (void)in_sizes; (void)n_in; (void)out_size; (void)ws_size;
    const float* x    = (const float*)d_in[0];
    const float* h0in = (const float*)d_in[1];
    const float* Wih0 = (const float*)d_in[2];
    const float* Whh0 = (const float*)d_in[3];
    const float* bih0 = (const float*)d_in[4];
    const float* bhh0 = (const float*)d_in[5];
    const float* Wih1 = (const float*)d_in[6];
    const float* Whh1 = (const float*)d_in[7];
    const float* bih1 = (const float*)d_in[8];
    const float* bhh1 = (const float*)d_in[9];
    const float* Wh0  = (const float*)d_in[10];
    const float* bh0  = (const float*)d_in[11];
    const float* Wh1  = (const float*)d_in[12];
    const float* bh1  = (const float*)d_in[13];
    const float* Wout = (const float*)d_in[14];

    float* ws = (float*)d_ws;
    float* zb = ws + OFF_ZB;
    float* P0 = ws + OFF_P0;
    u16*   pk = (u16*)(ws + OFF_P0);   // overlays P0, written after rnn consumed it
    float* out = (float*)d_out;

    p0_kernel<<<T_LEN - 1, 256, 0, stream>>>(x, Wih0, bih0, bhh0, P0);
    rnn_kernel<<<B_SZ, 128, 0, stream>>>(P0, h0in, Whh0, Wih1, Whh1, bih1, bhh1, zb, out);
    prep_pack<<<256, 256, 0, stream>>>(Wh1, Wh0, pk);
    ode_kernel<<<NSAMP / MBLK, 512, 0, stream>>>(zb, bh0, bh1, Wout, pk, out);
}

// Round 17
// 270.050 us; speedup vs baseline: 1.0515x; 1.0515x over previous
//
#include <hip/hip_runtime.h>
#include <math.h>

#define T_LEN 256
#define B_SZ  32
#define ZD    64
#define HD    256
#define NSAMP (B_SZ*(T_LEN-1))   // 8160
#define MBLK  32                 // samples per ODE block -> 255 blocks

typedef unsigned short u16;
typedef __attribute__((ext_vector_type(8))) _Float16 h8v;
typedef __attribute__((ext_vector_type(2))) _Float16 h2v;
typedef __attribute__((ext_vector_type(8))) unsigned short us8v;
typedef __attribute__((ext_vector_type(4))) float  f4v;

// ws layout (float offsets). Packs overlay P0 (prep runs AFTER rnn consumed P0).
#define SZ_ZB   (B_SZ*(T_LEN-1)*ZD)     // 522240
#define SZ_P0   ((T_LEN-1)*B_SZ*ZD)     // 522240 (plain [s][b][j] layout)
#define OFF_ZB  0
#define OFF_P0  (OFF_ZB + SZ_ZB)
// fp16 pack offsets in u16 units, based at (u16*)(ws + OFF_P0); 163840 u16 = 320KB <= P0 region
#define PK_WB  0         // Wh1^T fragments (phase B), 65536
#define PK_WC  65536     // Wh1 fragments (phase C), 65536
#define PK_WA  131072    // Wh0^T fragments (phase A), 16384
#define PK_WD  147456    // Wh0 fragments (phase D), 16384

__device__ __forceinline__ u16 f2h(float x) {
    _Float16 h = (_Float16)x;
    return __builtin_bit_cast(u16, h);
}
__device__ __forceinline__ float fast_tanh(float x) {
    float xc = fminf(fmaxf(x, -18.f), 18.f);
    float e2 = __builtin_amdgcn_exp2f(xc * 2.8853900817779268f);  // e^(2x)
    return (e2 - 1.f) * __builtin_amdgcn_rcpf(e2 + 1.f);
}
__device__ __forceinline__ f4v mfma16h(h8v a, h8v b, f4v c) {
    return __builtin_amdgcn_mfma_f32_16x16x32_f16(a, b, c, 0, 0, 0);
}
__device__ __forceinline__ h8v lds_frag(const u16* buf, int byt) {
    return *(const h8v*)((const char*)buf + byt);
}
__device__ __forceinline__ void store_h(u16* buf, int byt, float v) {
    *(u16*)((char*)buf + byt) = f2h(v);
}
// LDS-only barrier: does NOT drain vmcnt (global loads/stores stay in flight).
__device__ __forceinline__ void barrier_lds() {
    asm volatile("s_waitcnt lgkmcnt(0)\n\ts_barrier" ::: "memory");
}

__device__ __forceinline__ h2v bch2(unsigned u) { return __builtin_bit_cast(h2v, u); }
__device__ __forceinline__ unsigned packh2(float a, float b) {
    h2v v; v[0] = (_Float16)a; v[1] = (_Float16)b;
    return __builtin_bit_cast(unsigned, v);
}
#if __has_builtin(__builtin_amdgcn_fdot2)
__device__ __forceinline__ float fdot2f(unsigned a, unsigned b, float c) {
    return __builtin_amdgcn_fdot2(bch2(a), bch2(b), c, false);
}
#else
__device__ __forceinline__ float fdot2f(unsigned a, unsigned b, float c) {
    h2v x = bch2(a), y = bch2(b);
    return c + (float)x[0] * (float)y[0] + (float)x[1] * (float)y[1];
}
#endif

// Yoshida coefficients * h_step (h=0.02). e%7: even=drift(+cs*h on q from dHp), odd=kick(-ds*h on p from dHq)
__device__ __constant__ float c_coef[7] = {
     0.013512071919596578f,
    -0.027024143839193156f,
    -0.003512071919596575f,
     0.034048287678386313f,
    -0.003512071919596575f,
    -0.027024143839193156f,
     0.013512071919596578f
};

// ---------------- prep: pack fp16 weights into MFMA B-fragment order ----------
// frag (nt,ks): lane = lg*16+col16 holds B[ks*32+lg*8+i][nt*16+col16], i=0..7
// idx = ((nt*KS + ks)*64 + lane)*8 + i
__global__ __launch_bounds__(256) void prep_pack(
    const float* __restrict__ Wh1, const float* __restrict__ Wh0, u16* __restrict__ pk)
{
    int i = blockIdx.x * 256 + threadIdx.x;      // 0..65535
    u16 h = f2h(Wh1[i]);
    {   // WB: B[k][n] = Wh1[n][k]; n=i>>8, k=i&255 (KS=8)
        int n = i >> 8, k = i & 255;
        int idx = ((((n >> 4) * 8 + (k >> 5)) * 64) + ((k >> 3) & 3) * 16 + (n & 15)) * 8 + (k & 7);
        pk[PK_WB + idx] = h;
    }
    {   // WC: B[k][n] = Wh1[k][n]; k=i>>8, n=i&255 (KS=8)
        int k = i >> 8, n = i & 255;
        int idx = ((((n >> 4) * 8 + (k >> 5)) * 64) + ((k >> 3) & 3) * 16 + (n & 15)) * 8 + (k & 7);
        pk[PK_WC + idx] = h;
    }
    if (i < HD * ZD) {
        u16 h0 = f2h(Wh0[i]);                    // Wh0[256][64]
        {   // WA: B[k][n] = Wh0[n][k]; n=i>>6 (0..255), k=i&63 (KS=2)
            int n = i >> 6, k = i & 63;
            int idx = ((((n >> 4) * 2 + (k >> 5)) * 64) + ((k >> 3) & 3) * 16 + (n & 15)) * 8 + (k & 7);
            pk[PK_WA + idx] = h0;
        }
        {   // WD: B[k][n] = Wh0[k][n]; k=i>>6, n=i&63 (KS=8, NT=4)
            int k = i >> 6, n = i & 63;
            int idx = ((((n >> 4) * 8 + (k >> 5)) * 64) + ((k >> 3) & 3) * 16 + (n & 15)) * 8 + (k & 7);
            pk[PK_WD + idx] = h0;
        }
    }
}

// ---------------- P0 = x[:,255-s,:] @ Wih0^T + bih0 + bhh0,  P0[s][b][j] -------
__global__ __launch_bounds__(256) void p0_kernel(
    const float* __restrict__ x, const float* __restrict__ Wih0,
    const float* __restrict__ bih0, const float* __restrict__ bhh0,
    float* __restrict__ P0)
{
    __shared__ float xs[B_SZ * 128];
    int s = blockIdx.x;
    int t = (T_LEN - 1) - s;
    int tid = threadIdx.x;
#pragma unroll
    for (int p = 0; p < 4; ++p) {
        int idx4 = tid + p * 256;
        int b = idx4 >> 5;
        int k = (idx4 & 31) * 4;
        *(float4*)&xs[b * 128 + k] = *(const float4*)&x[b * (T_LEN * 128) + t * 128 + k];
    }
    int j = tid & 63, bq = tid >> 6;
    float wr[128];
#pragma unroll
    for (int k4 = 0; k4 < 32; ++k4) {
        float4 v = *(const float4*)&Wih0[j * 128 + k4 * 4];
        wr[k4*4+0]=v.x; wr[k4*4+1]=v.y; wr[k4*4+2]=v.z; wr[k4*4+3]=v.w;
    }
    float bias = bih0[j] + bhh0[j];
    __syncthreads();
    for (int p = 0; p < 8; ++p) {
        int b = bq * 8 + p;
        float a0 = bias, a1 = 0.f;
#pragma unroll
        for (int k4 = 0; k4 < 32; ++k4) {
            float4 v = *(const float4*)&xs[b * 128 + k4 * 4];
            a0 += v.x * wr[k4*4+0] + v.y * wr[k4*4+1];
            a1 += v.z * wr[k4*4+2] + v.w * wr[k4*4+3];
        }
        P0[(s * B_SZ + b) * ZD + j] = a0 + a1;
    }
}

// ---------------- RNN scan: 32 blocks (1/batch), 2 waves, fdot2 + fp16 state --
__global__ __launch_bounds__(128, 1) void rnn_kernel(
    const float* __restrict__ P0, const float* __restrict__ h0in,
    const float* __restrict__ Whh0, const float* __restrict__ Wih1,
    const float* __restrict__ Whh1, const float* __restrict__ bih1,
    const float* __restrict__ bhh1,
    float* __restrict__ zbuf, float* __restrict__ out)
{
    __shared__ __align__(16) u16 h0buf[2][ZD];
    __shared__ __align__(16) u16 h1buf[2][ZD];
    const int b = blockIdx.x;
    const int tid = threadIdx.x;
    const int w = tid >> 6, j = tid & 63;

    unsigned wa[32], wb[32];
    float bias1 = 0.f;
    if (w == 0) {
#pragma unroll
        for (int q = 0; q < 16; ++q) {
            float4 v = *(const float4*)&Whh0[j * 64 + q * 4];
            wa[q*2+0] = packh2(v.x, v.y);
            wa[q*2+1] = packh2(v.z, v.w);
        }
        h0buf[0][j] = f2h(h0in[j]);
    } else {
#pragma unroll
        for (int q = 0; q < 16; ++q) {
            float4 v = *(const float4*)&Wih1[j * 64 + q * 4];
            wa[q*2+0] = packh2(v.x, v.y);
            wa[q*2+1] = packh2(v.z, v.w);
            float4 u = *(const float4*)&Whh1[j * 64 + q * 4];
            wb[q*2+0] = packh2(u.x, u.y);
            wb[q*2+1] = packh2(u.z, u.w);
        }
        bias1 = bih1[j] + bhh1[j];
        h1buf[0][j] = f2h(h0in[ZD + j]);
    }
    float a_cur = 0.f, a_nxt = 0.f;
    if (w == 0) {
        a_cur = P0[(0 * B_SZ + b) * ZD + j];
        a_nxt = P0[(1 * B_SZ + b) * ZD + j];
    }
    __syncthreads();

    for (int t = 0; t < T_LEN; ++t) {
        if (w == 0) {
            if (t < T_LEN - 1) {
                float a_new = (t + 2 < T_LEN - 1) ? P0[((t + 2) * B_SZ + b) * ZD + j] : 0.f;
                const u16* hp = h0buf[t & 1];
                float c0 = a_cur, c1 = 0.f, c2 = 0.f, c3 = 0.f;
#pragma unroll
                for (int pp = 0; pp < 8; ++pp) {
                    uint4 ha = *(const uint4*)(hp + pp * 8);
                    c0 = fdot2f(wa[pp*4+0], ha.x, c0);
                    c1 = fdot2f(wa[pp*4+1], ha.y, c1);
                    c2 = fdot2f(wa[pp*4+2], ha.z, c2);
                    c3 = fdot2f(wa[pp*4+3], ha.w, c3);
                }
                float y = fast_tanh((c0 + c1) + (c2 + c3));
                h0buf[(t & 1) ^ 1][j] = f2h(y);
                a_cur = a_nxt; a_nxt = a_new;
            }
        } else {
            if (t >= 1) {
                const u16* hp = h0buf[t & 1];         // y0[t-1]
                const u16* gp = h1buf[(t + 1) & 1];   // y1[t-2]
                float c0 = bias1, c1 = 0.f, c2 = 0.f, c3 = 0.f;
                float d0 = 0.f, d1 = 0.f, d2 = 0.f, d3 = 0.f;
#pragma unroll
                for (int pp = 0; pp < 8; ++pp) {
                    uint4 ha = *(const uint4*)(hp + pp * 8);
                    uint4 ga = *(const uint4*)(gp + pp * 8);
                    c0 = fdot2f(wa[pp*4+0], ha.x, c0);
                    c1 = fdot2f(wa[pp*4+1], ha.y, c1);
                    c2 = fdot2f(wa[pp*4+2], ha.z, c2);
                    c3 = fdot2f(wa[pp*4+3], ha.w, c3);
                    d0 = fdot2f(wb[pp*4+0], ga.x, d0);
                    d1 = fdot2f(wb[pp*4+1], ga.y, d1);
                    d2 = fdot2f(wb[pp*4+2], ga.z, d2);
                    d3 = fdot2f(wb[pp*4+3], ga.w, d3);
                }
                float y = fast_tanh(((c0 + c1) + (c2 + c3)) + ((d0 + d1) + (d2 + d3)));
                h1buf[t & 1][j] = f2h(y);
                int s = t - 1;
                int tau = (T_LEN - 2) - s;
                zbuf[(b * (T_LEN - 1) + tau) * ZD + j] = y;
                if (s == 0)
                    out[(b * T_LEN + (T_LEN - 1)) * ZD + j] = y;
            }
        }
        barrier_lds();   // orders h0 handoff; global loads/stores stay in flight
    }
}

// ---------------- ODE: MBLK=32, 512 thr, time-shared wgt (round-13 optimum) ---
__global__ __launch_bounds__(512, 1) void ode_kernel(
    const float* __restrict__ zbuf,
    const float* __restrict__ bh0, const float* __restrict__ bh1,
    const float* __restrict__ Wout, const u16* __restrict__ pk,
    float* __restrict__ out)
{
    __shared__ __align__(16) u16 sWA[16384];   // 32KB, WA frags
    __shared__ __align__(16) u16 sWD[16384];   // 32KB, WD frags
    __shared__ __align__(16) u16 aA[32 * 256]; // 16KB, swizzled fp16 activations
    __shared__ __align__(16) u16 aB[32 * 256]; // 16KB
    __shared__ __align__(16) u16 zh[32 * 64];  // 4KB, swizzled fp16 z
    __shared__ __align__(16) float zq[32 * 64];// 8KB, fp32 z state

    const int tid  = threadIdx.x;
    const int w    = tid >> 6, lane = tid & 63;
    const int l15  = lane & 15, lg = lane >> 4;
    const int base = blockIdx.x * MBLK;

    const h8v* pWB = (const h8v*)(pk + PK_WB);
    const h8v* pWC = (const h8v*)(pk + PK_WC);

    // ---- time-shared weight block: starts as WB
    h8v wgt[2][8];
#pragma unroll
    for (int t = 0; t < 2; ++t)
#pragma unroll
        for (int ks = 0; ks < 8; ++ks)
            wgt[t][ks] = pWB[((w * 2 + t) * 8 + ks) * 64 + lane];

    // ---- stage WA/WD into LDS (pack order)
    {
        const us8v* gA = (const us8v*)(pk + PK_WA);
        const us8v* gD = (const us8v*)(pk + PK_WD);
#pragma unroll
        for (int r = 0; r < 4; ++r) {
            int idx = tid + r * 512;             // 2048 vec8 per 32KB
            ((us8v*)sWA)[idx] = gA[idx];
            ((us8v*)sWD)[idx] = gD[idx];
        }
    }

    float bh0v[2], bh1v[2], wov[2];
#pragma unroll
    for (int t = 0; t < 2; ++t) {
        int col = (w * 2 + t) * 16 + l15;
        bh0v[t] = bh0[col]; bh1v[t] = bh1[col]; wov[t] = Wout[col];
    }

    // ---- stage z tile (32x64): zq f32 + zh swizzled fp16
    {
        int m = tid >> 4, c4 = tid & 15;
        float4 v = *(const float4*)&zbuf[(size_t)(base + m) * ZD + c4 * 4];
        *(float4*)&zq[m * 64 + c4 * 4] = v;
        ushort4 hh;
        hh.x = f2h(v.x); hh.y = f2h(v.y); hh.z = f2h(v.z); hh.w = f2h(v.w);
        int byt = (m * 128 + c4 * 8) ^ ((m & 7) << 4);
        *(ushort4*)((char*)zh + byt) = hh;
    }
    __syncthreads();

#pragma unroll 1
    for (int e = 0; e < 28; ++e) {
        int ei = e % 7;
        f4v acc[2][2];
#pragma unroll
        for (int mt = 0; mt < 2; ++mt)
#pragma unroll
            for (int t = 0; t < 2; ++t) acc[mt][t] = f4v{0.f, 0.f, 0.f, 0.f};

        // ---- Phase A: pre0 = z @ Wh0^T (K=64; wave w owns nt = 2w, 2w+1)
#pragma unroll
        for (int ks = 0; ks < 2; ++ks) {
            h8v az[2];
#pragma unroll
            for (int mt = 0; mt < 2; ++mt) {
                int byt = ((mt * 16 + l15) * 128 + ks * 64 + lg * 16) ^ ((l15 & 7) << 4);
                az[mt] = lds_frag(zh, byt);
            }
#pragma unroll
            for (int t = 0; t < 2; ++t) {
                h8v bw = lds_frag(sWA, (((w * 2 + t) * 2 + ks) * 64 + lane) * 16);
#pragma unroll
                for (int mt = 0; mt < 2; ++mt)
                    acc[mt][t] = mfma16h(az[mt], bw, acc[mt][t]);
            }
        }
#pragma unroll
        for (int mt = 0; mt < 2; ++mt)
#pragma unroll
            for (int t = 0; t < 2; ++t)
#pragma unroll
                for (int r = 0; r < 4; ++r) {
                    float tv = fast_tanh(acc[mt][t][r] + bh0v[t]);
                    int row = mt * 16 + lg * 4 + r;
                    int col = (w * 2 + t) * 16 + l15;
                    store_h(aA, (row * 512 + col * 2) ^ ((row & 7) << 4), tv);
                }
        __syncthreads();

        // ---- Phase B: pre1 = h0 @ Wh1^T (wgt = WB); g -> aB
#pragma unroll
        for (int mt = 0; mt < 2; ++mt)
#pragma unroll
            for (int t = 0; t < 2; ++t) acc[mt][t] = f4v{0.f, 0.f, 0.f, 0.f};
#pragma unroll
        for (int ks = 0; ks < 8; ++ks) {
            h8v ah[2];
#pragma unroll
            for (int mt = 0; mt < 2; ++mt) {
                int byt = ((mt * 16 + l15) * 512 + ks * 64 + lg * 16) ^ ((l15 & 7) << 4);
                ah[mt] = lds_frag(aA, byt);
            }
#pragma unroll
            for (int t = 0; t < 2; ++t)
#pragma unroll
                for (int mt = 0; mt < 2; ++mt)
                    acc[mt][t] = mfma16h(ah[mt], wgt[t][ks], acc[mt][t]);
        }
#pragma unroll
        for (int mt = 0; mt < 2; ++mt)
#pragma unroll
            for (int t = 0; t < 2; ++t)
#pragma unroll
                for (int r = 0; r < 4; ++r) {
                    float tv = fast_tanh(acc[mt][t][r] + bh1v[t]);
                    float g = wov[t] * (1.f - tv * tv);
                    int row = mt * 16 + lg * 4 + r;
                    int col = (w * 2 + t) * 16 + l15;
                    store_h(aB, (row * 512 + col * 2) ^ ((row & 7) << 4), g);
                }
        // swap weight block to WC (WAR on wgt orders after last B-MFMA; latency
        // hides under barrier + C's LDS reads)
#pragma unroll
        for (int t = 0; t < 2; ++t)
#pragma unroll
            for (int ks = 0; ks < 8; ++ks)
                wgt[t][ks] = pWC[((w * 2 + t) * 8 + ks) * 64 + lane];
        __syncthreads();

        // ---- Phase C: u = (g @ Wh1) * (1 - h0^2)  (wgt = WC); u -> aA in place
#pragma unroll
        for (int mt = 0; mt < 2; ++mt)
#pragma unroll
            for (int t = 0; t < 2; ++t) acc[mt][t] = f4v{0.f, 0.f, 0.f, 0.f};
#pragma unroll
        for (int ks = 0; ks < 8; ++ks) {
            h8v ah[2];
#pragma unroll
            for (int mt = 0; mt < 2; ++mt) {
                int byt = ((mt * 16 + l15) * 512 + ks * 64 + lg * 16) ^ ((l15 & 7) << 4);
                ah[mt] = lds_frag(aB, byt);
            }
#pragma unroll
            for (int t = 0; t < 2; ++t)
#pragma unroll
                for (int mt = 0; mt < 2; ++mt)
                    acc[mt][t] = mfma16h(ah[mt], wgt[t][ks], acc[mt][t]);
        }
#pragma unroll
        for (int mt = 0; mt < 2; ++mt)
#pragma unroll
            for (int t = 0; t < 2; ++t)
#pragma unroll
                for (int r = 0; r < 4; ++r) {
                    int row = mt * 16 + lg * 4 + r;
                    int col = (w * 2 + t) * 16 + l15;
                    int byt = (row * 512 + col * 2) ^ ((row & 7) << 4);
                    float hv = (float)__builtin_bit_cast(_Float16, *(const u16*)((const char*)aA + byt));
                    float u = acc[mt][t][r] * (1.f - hv * hv);
                    *(u16*)((char*)aA + byt) = f2h(u);   // single-owner slot
                }
        // swap weight block back to WB for next eval (hides under phase D)
#pragma unroll
        for (int t = 0; t < 2; ++t)
#pragma unroll
            for (int ks = 0; ks < 8; ++ks)
                wgt[t][ks] = pWB[((w * 2 + t) * 8 + ks) * 64 + lane];
        __syncthreads();

        // ---- Phase D (waves 4-7): dz = u @ Wh0 (N=64); update zq/zh
        if (w >= 4) {
            int nt = w - 4;
            f4v accd[2];
            accd[0] = f4v{0.f, 0.f, 0.f, 0.f};
            accd[1] = f4v{0.f, 0.f, 0.f, 0.f};
#pragma unroll
            for (int ks = 0; ks < 8; ++ks) {
                h8v ah[2];
#pragma unroll
                for (int mt = 0; mt < 2; ++mt) {
                    int byt = ((mt * 16 + l15) * 512 + ks * 64 + lg * 16) ^ ((l15 & 7) << 4);
                    ah[mt] = lds_frag(aA, byt);
                }
                h8v bw = lds_frag(sWD, ((nt * 8 + ks) * 64 + lane) * 16);
#pragma unroll
                for (int mt = 0; mt < 2; ++mt)
                    accd[mt] = mfma16h(ah[mt], bw, accd[mt]);
            }
            float cf = c_coef[ei];
            int col = nt * 16 + l15;
            bool drift = (ei & 1) == 0;
            bool active = drift ? (col >= 32) : (col < 32);
            int dcol = drift ? (col - 32) : (col + 32);
            if (active) {
#pragma unroll
                for (int mt = 0; mt < 2; ++mt)
#pragma unroll
                    for (int r = 0; r < 4; ++r) {
                        int row = mt * 16 + lg * 4 + r;
                        float nz = zq[row * 64 + dcol] + cf * accd[mt][r];
                        zq[row * 64 + dcol] = nz;
                        store_h(zh, (row * 128 + dcol * 2) ^ ((row & 7) << 4), nz);
                    }
            }
        }
        __syncthreads();
    }

    // ---- write out[b][tau][:] = z
    {
        int m = tid >> 4, c4 = tid & 15;
        int sidx = base + m;
        int b = sidx / 255;
        int tau = sidx - b * 255;
        float4 v = *(const float4*)&zq[m * 64 + c4 * 4];
        *(float4*)&out[((size_t)(b * T_LEN + tau)) * ZD + c4 * 4] = v;
    }
}

extern "C" void kernel_launch(void* const* d_in, const int* in_sizes, int n_in,
                              void* d_out, int out_size, void* d_ws, size_t ws_size,
                              hipStream_t stream)
{
    (void)in_sizes; (void)n_in; (void)out_size; (void)ws_size;
    const float* x    = (const float*)d_in[0];
    const float* h0in = (const float*)d_in[1];
    const float* Wih0 = (const float*)d_in[2];
    const float* Whh0 = (const float*)d_in[3];
    const float* bih0 = (const float*)d_in[4];
    const float* bhh0 = (const float*)d_in[5];
    const float* Wih1 = (const float*)d_in[6];
    const float* Whh1 = (const float*)d_in[7];
    const float* bih1 = (const float*)d_in[8];
    const float* bhh1 = (const float*)d_in[9];
    const float* Wh0  = (const float*)d_in[10];
    const float* bh0  = (const float*)d_in[11];
    const float* Wh1  = (const float*)d_in[12];
    const float* bh1  = (const float*)d_in[13];
    const float* Wout = (const float*)d_in[14];

    float* ws = (float*)d_ws;
    float* zb = ws + OFF_ZB;
    float* P0 = ws + OFF_P0;
    u16*   pk = (u16*)(ws + OFF_P0);   // overlays P0, written after rnn consumed it
    float* out = (float*)d_out;

    p0_kernel<<<T_LEN - 1, 256, 0, stream>>>(x, Wih0, bih0, bhh0, P0);
    rnn_kernel<<<B_SZ, 128, 0, stream>>>(P0, h0in, Whh0, Wih1, Whh1, bih1, bhh1, zb, out);
    prep_pack<<<256, 256, 0, stream>>>(Wh1, Wh0, pk);
    ode_kernel<<<NSAMP / MBLK, 512, 0, stream>>>(zb, bh0, bh1, Wout, pk, out);
}

// Round 18
// 233.990 us; speedup vs baseline: 1.2135x; 1.1541x over previous
//
#include <hip/hip_runtime.h>
#include <math.h>

#define T_LEN 256
#define B_SZ  32
#define ZD    64
#define HD    256
#define NSAMP (B_SZ*(T_LEN-1))   // 8160
#define MBLK  32                 // samples per ODE block -> 255 blocks

typedef unsigned short u16;
typedef __attribute__((ext_vector_type(8))) _Float16 h8v;
typedef __attribute__((ext_vector_type(2))) _Float16 h2v;
typedef __attribute__((ext_vector_type(8))) unsigned short us8v;
typedef __attribute__((ext_vector_type(4))) float  f4v;

// ws layout (float offsets). Packs overlay P0 (prep runs AFTER rnn consumed P0).
#define SZ_ZB   (B_SZ*(T_LEN-1)*ZD)     // 522240
#define SZ_P0   ((T_LEN-1)*B_SZ*ZD)     // 522240 (plain [s][b][j] layout)
#define OFF_ZB  0
#define OFF_P0  (OFF_ZB + SZ_ZB)
// fp16 pack offsets in u16 units, based at (u16*)(ws + OFF_P0); 163840 u16 = 320KB <= P0 region
#define PK_WB  0         // Wh1^T fragments (phase B), 65536
#define PK_WC  65536     // Wh1 fragments (phase C), 65536
#define PK_WA  131072    // Wh0^T fragments (phase A), 16384
#define PK_WD  147456    // Wh0 fragments (phase D), 16384

__device__ __forceinline__ u16 f2h(float x) {
    _Float16 h = (_Float16)x;
    return __builtin_bit_cast(u16, h);
}
__device__ __forceinline__ float fast_tanh(float x) {
    float xc = fminf(fmaxf(x, -18.f), 18.f);
    float e2 = __builtin_amdgcn_exp2f(xc * 2.8853900817779268f);  // e^(2x)
    return (e2 - 1.f) * __builtin_amdgcn_rcpf(e2 + 1.f);
}
__device__ __forceinline__ f4v mfma16h(h8v a, h8v b, f4v c) {
    return __builtin_amdgcn_mfma_f32_16x16x32_f16(a, b, c, 0, 0, 0);
}
__device__ __forceinline__ h8v lds_frag(const u16* buf, int byt) {
    return *(const h8v*)((const char*)buf + byt);
}
__device__ __forceinline__ void store_h(u16* buf, int byt, float v) {
    *(u16*)((char*)buf + byt) = f2h(v);
}
// LDS-only barrier: does NOT drain vmcnt (global loads/stores stay in flight).
__device__ __forceinline__ void barrier_lds() {
    asm volatile("s_waitcnt lgkmcnt(0)\n\ts_barrier" ::: "memory");
}

__device__ __forceinline__ h2v bch2(unsigned u) { return __builtin_bit_cast(h2v, u); }
__device__ __forceinline__ unsigned packh2(float a, float b) {
    h2v v; v[0] = (_Float16)a; v[1] = (_Float16)b;
    return __builtin_bit_cast(unsigned, v);
}
#if __has_builtin(__builtin_amdgcn_fdot2)
__device__ __forceinline__ float fdot2f(unsigned a, unsigned b, float c) {
    return __builtin_amdgcn_fdot2(bch2(a), bch2(b), c, false);
}
#else
__device__ __forceinline__ float fdot2f(unsigned a, unsigned b, float c) {
    h2v x = bch2(a), y = bch2(b);
    return c + (float)x[0] * (float)y[0] + (float)x[1] * (float)y[1];
}
#endif

// Yoshida coefficients * h_step (h=0.02). e%7: even=drift(+cs*h on q from dHp), odd=kick(-ds*h on p from dHq)
__device__ __constant__ float c_coef[7] = {
     0.013512071919596578f,
    -0.027024143839193156f,
    -0.003512071919596575f,
     0.034048287678386313f,
    -0.003512071919596575f,
    -0.027024143839193156f,
     0.013512071919596578f
};

// ---------------- prep: pack fp16 weights into MFMA B-fragment order ----------
// frag (nt,ks): lane = lg*16+col16 holds B[ks*32+lg*8+i][nt*16+col16], i=0..7
// idx = ((nt*KS + ks)*64 + lane)*8 + i
__global__ __launch_bounds__(256) void prep_pack(
    const float* __restrict__ Wh1, const float* __restrict__ Wh0, u16* __restrict__ pk)
{
    int i = blockIdx.x * 256 + threadIdx.x;      // 0..65535
    u16 h = f2h(Wh1[i]);
    {   // WB: B[k][n] = Wh1[n][k]; n=i>>8, k=i&255 (KS=8)
        int n = i >> 8, k = i & 255;
        int idx = ((((n >> 4) * 8 + (k >> 5)) * 64) + ((k >> 3) & 3) * 16 + (n & 15)) * 8 + (k & 7);
        pk[PK_WB + idx] = h;
    }
    {   // WC: B[k][n] = Wh1[k][n]; k=i>>8, n=i&255 (KS=8)
        int k = i >> 8, n = i & 255;
        int idx = ((((n >> 4) * 8 + (k >> 5)) * 64) + ((k >> 3) & 3) * 16 + (n & 15)) * 8 + (k & 7);
        pk[PK_WC + idx] = h;
    }
    if (i < HD * ZD) {
        u16 h0 = f2h(Wh0[i]);                    // Wh0[256][64]
        {   // WA: B[k][n] = Wh0[n][k]; n=i>>6 (0..255), k=i&63 (KS=2)
            int n = i >> 6, k = i & 63;
            int idx = ((((n >> 4) * 2 + (k >> 5)) * 64) + ((k >> 3) & 3) * 16 + (n & 15)) * 8 + (k & 7);
            pk[PK_WA + idx] = h0;
        }
        {   // WD: B[k][n] = Wh0[k][n]; k=i>>6, n=i&63 (KS=8, NT=4)
            int k = i >> 6, n = i & 63;
            int idx = ((((n >> 4) * 8 + (k >> 5)) * 64) + ((k >> 3) & 3) * 16 + (n & 15)) * 8 + (k & 7);
            pk[PK_WD + idx] = h0;
        }
    }
}

// ---------------- P0 = x[:,255-s,:] @ Wih0^T + bih0 + bhh0,  P0[s][b][j] -------
__global__ __launch_bounds__(256) void p0_kernel(
    const float* __restrict__ x, const float* __restrict__ Wih0,
    const float* __restrict__ bih0, const float* __restrict__ bhh0,
    float* __restrict__ P0)
{
    __shared__ float xs[B_SZ * 128];
    int s = blockIdx.x;
    int t = (T_LEN - 1) - s;
    int tid = threadIdx.x;
#pragma unroll
    for (int p = 0; p < 4; ++p) {
        int idx4 = tid + p * 256;
        int b = idx4 >> 5;
        int k = (idx4 & 31) * 4;
        *(float4*)&xs[b * 128 + k] = *(const float4*)&x[b * (T_LEN * 128) + t * 128 + k];
    }
    int j = tid & 63, bq = tid >> 6;
    float wr[128];
#pragma unroll
    for (int k4 = 0; k4 < 32; ++k4) {
        float4 v = *(const float4*)&Wih0[j * 128 + k4 * 4];
        wr[k4*4+0]=v.x; wr[k4*4+1]=v.y; wr[k4*4+2]=v.z; wr[k4*4+3]=v.w;
    }
    float bias = bih0[j] + bhh0[j];
    __syncthreads();
    for (int p = 0; p < 8; ++p) {
        int b = bq * 8 + p;
        float a0 = bias, a1 = 0.f;
#pragma unroll
        for (int k4 = 0; k4 < 32; ++k4) {
            float4 v = *(const float4*)&xs[b * 128 + k4 * 4];
            a0 += v.x * wr[k4*4+0] + v.y * wr[k4*4+1];
            a1 += v.z * wr[k4*4+2] + v.w * wr[k4*4+3];
        }
        P0[(s * B_SZ + b) * ZD + j] = a0 + a1;
    }
}

// ---------------- RNN scan: 32 blocks (1/batch), 2 waves, fdot2 + fp16 state --
// Tick t (256 ticks, one LDS barrier each):
//   wave0 (t<255):  y0[t] = tanh(P0[t] + Whh0 . y0[t-1])   y0[-1]=h0init
//   wave1 (t>=1):   y1[t-1] = tanh(b1 + Wih1 . y0[t-1] + Whh1 . y1[t-2])
// Weights fp16-packed in VGPRs (wave0: 32 regs, wave1: 64); h-state fp16 in LDS,
// read as uniform-address (broadcast, conflict-free) b128 loads.
__global__ __launch_bounds__(128, 1) void rnn_kernel(
    const float* __restrict__ P0, const float* __restrict__ h0in,
    const float* __restrict__ Whh0, const float* __restrict__ Wih1,
    const float* __restrict__ Whh1, const float* __restrict__ bih1,
    const float* __restrict__ bhh1,
    float* __restrict__ zbuf, float* __restrict__ out)
{
    __shared__ __align__(16) u16 h0buf[2][ZD];
    __shared__ __align__(16) u16 h1buf[2][ZD];
    const int b = blockIdx.x;
    const int tid = threadIdx.x;
    const int w = tid >> 6, j = tid & 63;

    unsigned wa[32], wb[32];
    float bias1 = 0.f;
    if (w == 0) {
#pragma unroll
        for (int q = 0; q < 16; ++q) {
            float4 v = *(const float4*)&Whh0[j * 64 + q * 4];
            wa[q*2+0] = packh2(v.x, v.y);
            wa[q*2+1] = packh2(v.z, v.w);
        }
        h0buf[0][j] = f2h(h0in[j]);
    } else {
#pragma unroll
        for (int q = 0; q < 16; ++q) {
            float4 v = *(const float4*)&Wih1[j * 64 + q * 4];
            wa[q*2+0] = packh2(v.x, v.y);
            wa[q*2+1] = packh2(v.z, v.w);
            float4 u = *(const float4*)&Whh1[j * 64 + q * 4];
            wb[q*2+0] = packh2(u.x, u.y);
            wb[q*2+1] = packh2(u.z, u.w);
        }
        bias1 = bih1[j] + bhh1[j];
        h1buf[0][j] = f2h(h0in[ZD + j]);
    }
    float a_cur = 0.f, a_nxt = 0.f;
    if (w == 0) {
        a_cur = P0[(0 * B_SZ + b) * ZD + j];
        a_nxt = P0[(1 * B_SZ + b) * ZD + j];
    }
    __syncthreads();

    for (int t = 0; t < T_LEN; ++t) {
        if (w == 0) {
            if (t < T_LEN - 1) {
                float a_new = (t + 2 < T_LEN - 1) ? P0[((t + 2) * B_SZ + b) * ZD + j] : 0.f;
                const u16* hp = h0buf[t & 1];
                float c0 = a_cur, c1 = 0.f, c2 = 0.f, c3 = 0.f;
#pragma unroll
                for (int pp = 0; pp < 8; ++pp) {
                    uint4 ha = *(const uint4*)(hp + pp * 8);
                    c0 = fdot2f(wa[pp*4+0], ha.x, c0);
                    c1 = fdot2f(wa[pp*4+1], ha.y, c1);
                    c2 = fdot2f(wa[pp*4+2], ha.z, c2);
                    c3 = fdot2f(wa[pp*4+3], ha.w, c3);
                }
                float y = fast_tanh((c0 + c1) + (c2 + c3));
                h0buf[(t & 1) ^ 1][j] = f2h(y);
                a_cur = a_nxt; a_nxt = a_new;
            }
        } else {
            if (t >= 1) {
                const u16* hp = h0buf[t & 1];         // y0[t-1]
                const u16* gp = h1buf[(t + 1) & 1];   // y1[t-2]
                float c0 = bias1, c1 = 0.f, c2 = 0.f, c3 = 0.f;
                float d0 = 0.f, d1 = 0.f, d2 = 0.f, d3 = 0.f;
#pragma unroll
                for (int pp = 0; pp < 8; ++pp) {
                    uint4 ha = *(const uint4*)(hp + pp * 8);
                    uint4 ga = *(const uint4*)(gp + pp * 8);
                    c0 = fdot2f(wa[pp*4+0], ha.x, c0);
                    c1 = fdot2f(wa[pp*4+1], ha.y, c1);
                    c2 = fdot2f(wa[pp*4+2], ha.z, c2);
                    c3 = fdot2f(wa[pp*4+3], ha.w, c3);
                    d0 = fdot2f(wb[pp*4+0], ga.x, d0);
                    d1 = fdot2f(wb[pp*4+1], ga.y, d1);
                    d2 = fdot2f(wb[pp*4+2], ga.z, d2);
                    d3 = fdot2f(wb[pp*4+3], ga.w, d3);
                }
                float y = fast_tanh(((c0 + c1) + (c2 + c3)) + ((d0 + d1) + (d2 + d3)));
                h1buf[t & 1][j] = f2h(y);
                int s = t - 1;
                int tau = (T_LEN - 2) - s;
                zbuf[(b * (T_LEN - 1) + tau) * ZD + j] = y;
                if (s == 0)
                    out[(b * T_LEN + (T_LEN - 1)) * ZD + j] = y;
            }
        }
        barrier_lds();   // orders h0 handoff; global loads/stores stay in flight
    }
}

// ---------------- ODE: fp16 MFMA, weights resident (VGPR+LDS), 512 thr --------
// (Round-7 / bench-13 version verbatim: regWB+regWC dual-resident, h0reg.
//  Empirically fastest at ~152us; time-shared wgt variant measured +33us.)
__global__ __launch_bounds__(512, 1) void ode_kernel(
    const float* __restrict__ zbuf,
    const float* __restrict__ bh0, const float* __restrict__ bh1,
    const float* __restrict__ Wout, const u16* __restrict__ pk,
    float* __restrict__ out)
{
    __shared__ __align__(16) u16 sWA[16384];   // 32KB, WA frags
    __shared__ __align__(16) u16 sWD[16384];   // 32KB, WD frags
    __shared__ __align__(16) u16 aA[32 * 256]; // 16KB, swizzled fp16 activations
    __shared__ __align__(16) u16 aB[32 * 256]; // 16KB
    __shared__ __align__(16) u16 zh[32 * 64];  // 4KB, swizzled fp16 z
    __shared__ __align__(16) float zq[32 * 64];// 8KB, fp32 z state

    const int tid  = threadIdx.x;
    const int w    = tid >> 6, lane = tid & 63;
    const int l15  = lane & 15, lg = lane >> 4;
    const int base = blockIdx.x * MBLK;

    // ---- load Wh1 fragments into VGPRs (per wave: 2 nt-tiles each for B and C)
    h8v regWB[2][8], regWC[2][8];
    {
        const h8v* pWB = (const h8v*)(pk + PK_WB);
        const h8v* pWC = (const h8v*)(pk + PK_WC);
#pragma unroll
        for (int t = 0; t < 2; ++t)
#pragma unroll
            for (int ks = 0; ks < 8; ++ks) {
                int fi = ((w * 2 + t) * 8 + ks) * 64 + lane;
                regWB[t][ks] = pWB[fi];
                regWC[t][ks] = pWC[fi];
            }
    }
    // ---- stage WA/WD into LDS (pack order)
    {
        const us8v* gA = (const us8v*)(pk + PK_WA);
        const us8v* gD = (const us8v*)(pk + PK_WD);
#pragma unroll
        for (int r = 0; r < 4; ++r) {
            int idx = tid + r * 512;             // 2048 vec8 per 32KB
            ((us8v*)sWA)[idx] = gA[idx];
            ((us8v*)sWD)[idx] = gD[idx];
        }
    }

    float bh0v[2], bh1v[2], wov[2];
#pragma unroll
    for (int t = 0; t < 2; ++t) {
        int col = (w * 2 + t) * 16 + l15;
        bh0v[t] = bh0[col]; bh1v[t] = bh1[col]; wov[t] = Wout[col];
    }

    // ---- stage z tile (32x64): zq f32 + zh swizzled fp16
    {
        int m = tid >> 4, c4 = tid & 15;
        float4 v = *(const float4*)&zbuf[(size_t)(base + m) * ZD + c4 * 4];
        *(float4*)&zq[m * 64 + c4 * 4] = v;
        ushort4 hh;
        hh.x = f2h(v.x); hh.y = f2h(v.y); hh.z = f2h(v.z); hh.w = f2h(v.w);
        int byt = (m * 128 + c4 * 8) ^ ((m & 7) << 4);
        *(ushort4*)((char*)zh + byt) = hh;
    }
    __syncthreads();

#pragma unroll 1
    for (int e = 0; e < 28; ++e) {
        int ei = e % 7;
        f4v acc[2][2];
#pragma unroll
        for (int mt = 0; mt < 2; ++mt)
#pragma unroll
            for (int t = 0; t < 2; ++t) acc[mt][t] = f4v{0.f, 0.f, 0.f, 0.f};

        // ---- Phase A: pre0 = z @ Wh0^T (K=64, N=256; wave w owns nt=2w,2w+1)
#pragma unroll
        for (int ks = 0; ks < 2; ++ks) {
            h8v az[2];
#pragma unroll
            for (int mt = 0; mt < 2; ++mt) {
                int byt = ((mt * 16 + l15) * 128 + ks * 64 + lg * 16) ^ ((l15 & 7) << 4);
                az[mt] = lds_frag(zh, byt);
            }
#pragma unroll
            for (int t = 0; t < 2; ++t) {
                h8v bw = lds_frag(sWA, (((w * 2 + t) * 2 + ks) * 64 + lane) * 16);
#pragma unroll
                for (int mt = 0; mt < 2; ++mt)
                    acc[mt][t] = mfma16h(az[mt], bw, acc[mt][t]);
            }
        }
        float h0reg[2][2][4];
#pragma unroll
        for (int mt = 0; mt < 2; ++mt)
#pragma unroll
            for (int t = 0; t < 2; ++t)
#pragma unroll
                for (int r = 0; r < 4; ++r) {
                    float tv = fast_tanh(acc[mt][t][r] + bh0v[t]);
                    h0reg[mt][t][r] = tv;
                    int row = mt * 16 + lg * 4 + r;
                    int col = (w * 2 + t) * 16 + l15;
                    store_h(aA, (row * 512 + col * 2) ^ ((row & 7) << 4), tv);
                }
        __syncthreads();

        // ---- Phase B: pre1 = h0 @ Wh1^T; g = Wout*(1-tanh^2)
#pragma unroll
        for (int mt = 0; mt < 2; ++mt)
#pragma unroll
            for (int t = 0; t < 2; ++t) acc[mt][t] = f4v{0.f, 0.f, 0.f, 0.f};
#pragma unroll
        for (int ks = 0; ks < 8; ++ks) {
            h8v ah[2];
#pragma unroll
            for (int mt = 0; mt < 2; ++mt) {
                int byt = ((mt * 16 + l15) * 512 + ks * 64 + lg * 16) ^ ((l15 & 7) << 4);
                ah[mt] = lds_frag(aA, byt);
            }
#pragma unroll
            for (int t = 0; t < 2; ++t)
#pragma unroll
                for (int mt = 0; mt < 2; ++mt)
                    acc[mt][t] = mfma16h(ah[mt], regWB[t][ks], acc[mt][t]);
        }
#pragma unroll
        for (int mt = 0; mt < 2; ++mt)
#pragma unroll
            for (int t = 0; t < 2; ++t)
#pragma unroll
                for (int r = 0; r < 4; ++r) {
                    float tv = fast_tanh(acc[mt][t][r] + bh1v[t]);
                    float g = wov[t] * (1.f - tv * tv);
                    int row = mt * 16 + lg * 4 + r;
                    int col = (w * 2 + t) * 16 + l15;
                    store_h(aB, (row * 512 + col * 2) ^ ((row & 7) << 4), g);
                }
        __syncthreads();

        // ---- Phase C: u = (g @ Wh1) * (1 - h0^2), overwrite aA
#pragma unroll
        for (int mt = 0; mt < 2; ++mt)
#pragma unroll
            for (int t = 0; t < 2; ++t) acc[mt][t] = f4v{0.f, 0.f, 0.f, 0.f};
#pragma unroll
        for (int ks = 0; ks < 8; ++ks) {
            h8v ah[2];
#pragma unroll
            for (int mt = 0; mt < 2; ++mt) {
                int byt = ((mt * 16 + l15) * 512 + ks * 64 + lg * 16) ^ ((l15 & 7) << 4);
                ah[mt] = lds_frag(aB, byt);
            }
#pragma unroll
            for (int t = 0; t < 2; ++t)
#pragma unroll
                for (int mt = 0; mt < 2; ++mt)
                    acc[mt][t] = mfma16h(ah[mt], regWC[t][ks], acc[mt][t]);
        }
#pragma unroll
        for (int mt = 0; mt < 2; ++mt)
#pragma unroll
            for (int t = 0; t < 2; ++t)
#pragma unroll
                for (int r = 0; r < 4; ++r) {
                    float hv = h0reg[mt][t][r];
                    float u = acc[mt][t][r] * (1.f - hv * hv);
                    int row = mt * 16 + lg * 4 + r;
                    int col = (w * 2 + t) * 16 + l15;
                    store_h(aA, (row * 512 + col * 2) ^ ((row & 7) << 4), u);
                }
        __syncthreads();

        // ---- Phase D (waves 4-7): dz = u @ Wh0 (N=64); update zq/zh
        if (w >= 4) {
            int nt = w - 4;
            f4v accd[2];
            accd[0] = f4v{0.f, 0.f, 0.f, 0.f};
            accd[1] = f4v{0.f, 0.f, 0.f, 0.f};
#pragma unroll
            for (int ks = 0; ks < 8; ++ks) {
                h8v ah[2];
#pragma unroll
                for (int mt = 0; mt < 2; ++mt) {
                    int byt = ((mt * 16 + l15) * 512 + ks * 64 + lg * 16) ^ ((l15 & 7) << 4);
                    ah[mt] = lds_frag(aA, byt);
                }
                h8v bw = lds_frag(sWD, ((nt * 8 + ks) * 64 + lane) * 16);
#pragma unroll
                for (int mt = 0; mt < 2; ++mt)
                    accd[mt] = mfma16h(ah[mt], bw, accd[mt]);
            }
            float cf = c_coef[ei];
            int col = nt * 16 + l15;
            bool drift = (ei & 1) == 0;
            bool active = drift ? (col >= 32) : (col < 32);
            int dcol = drift ? (col - 32) : (col + 32);
            if (active) {
#pragma unroll
                for (int mt = 0; mt < 2; ++mt)
#pragma unroll
                    for (int r = 0; r < 4; ++r) {
                        int row = mt * 16 + lg * 4 + r;
                        float nz = zq[row * 64 + dcol] + cf * accd[mt][r];
                        zq[row * 64 + dcol] = nz;
                        store_h(zh, (row * 128 + dcol * 2) ^ ((row & 7) << 4), nz);
                    }
            }
        }
        __syncthreads();
    }

    // ---- write out[b][tau][:] = z
    {
        int m = tid >> 4, c4 = tid & 15;
        int sidx = base + m;
        int b = sidx / 255;
        int tau = sidx - b * 255;
        float4 v = *(const float4*)&zq[m * 64 + c4 * 4];
        *(float4*)&out[((size_t)(b * T_LEN + tau)) * ZD + c4 * 4] = v;
    }
}

extern "C" void kernel_launch(void* const* d_in, const int* in_sizes, int n_in,
                              void* d_out, int out_size, void* d_ws, size_t ws_size,
                              hipStream_t stream)
{
    (void)in_sizes; (void)n_in; (void)out_size; (void)ws_size;
    const float* x    = (const float*)d_in[0];
    const float* h0in = (const float*)d_in[1];
    const float* Wih0 = (const float*)d_in[2];
    const float* Whh0 = (const float*)d_in[3];
    const float* bih0 = (const float*)d_in[4];
    const float* bhh0 = (const float*)d_in[5];
    const float* Wih1 = (const float*)d_in[6];
    const float* Whh1 = (const float*)d_in[7];
    const float* bih1 = (const float*)d_in[8];
    const float* bhh1 = (const float*)d_in[9];
    const float* Wh0  = (const float*)d_in[10];
    const float* bh0  = (const float*)d_in[11];
    const float* Wh1  = (const float*)d_in[12];
    const float* bh1  = (const float*)d_in[13];
    const float* Wout = (const float*)d_in[14];

    float* ws = (float*)d_ws;
    float* zb = ws + OFF_ZB;
    float* P0 = ws + OFF_P0;
    u16*   pk = (u16*)(ws + OFF_P0);   // overlays P0, written after rnn consumed it
    float* out = (float*)d_out;

    p0_kernel<<<T_LEN - 1, 256, 0, stream>>>(x, Wih0, bih0, bhh0, P0);
    rnn_kernel<<<B_SZ, 128, 0, stream>>>(P0, h0in, Whh0, Wih1, Whh1, bih1, bhh1, zb, out);
    prep_pack<<<256, 256, 0, stream>>>(Wh1, Wh0, pk);
    ode_kernel<<<NSAMP / MBLK, 512, 0, stream>>>(zb, bh0, bh1, Wout, pk, out);
}